// Round 5
// baseline (129.050 us; speedup 1.0000x reference)
//
#include <hip/hip_runtime.h>
#include <math.h>

#define BATCH 16
#define NCLS 80
#define SUMHW 7581            // 76*76 + 38*38 + 19*19
#define NN 22743              // 3 anchors * SUMHW
#define ASTRIDE 7584          // padded per-anchor stride for so/xthr (7581 -> 7584, /4)
#define PADNN (3 * ASTRIDE)   // 22752
#define TOPK 128
#define CAP 1024              // fallback gather cap
#define GCAP 2048             // per-(b,c) global candidate list capacity (mean ~650)
#define STAGECAP 96           // per-class LDS staging cap in scatter (mean ~30, +12 sigma)
#define KEYBASE 0x3E800000u   // bits of 0.25f (fallback histogram base)
#define SBITS   0x3F19999Au   // bits of 0.6f

// exact sigmoid matching numpy f32 chain: correctly-rounded exp (double) -> f32 ops
__device__ __forceinline__ float sigf(float x) {
    float e = (float)exp(-(double)x);
    return 1.0f / (1.0f + e);
}
__device__ __forceinline__ float expf_cr(float x) {
    return (float)exp((double)x);
}

struct DecParams { float aw[9]; float ah[9]; };

// ---------------- Stage A: decode boxes + exact objectness + x-threshold ----------------
// xthr correctness:
//   Tp = 0.59999 (< 0.6f = 0.60000002384).  thr = -log(so/Tp - 1)  =>  sigmoid(thr) = Tp/so.
//   Capture needed: ex = fl(fl(sig(x))*so) >= 0.6f  =>  true sig(x)*so >= 0.6f*(1-2.4e-7)
//     => sig(x) >= 0.5999999/so > Tp/so  =>  x > thr_d >= thr_f32(rounded down)  => captured.
//   Miss safe: x <= thr_f32 <= thr_d  =>  true sig(x) <= Tp/so
//     => ex <= Tp*(1+3*2^-24) = 0.5999901 < 0.6f  => every missed element scores < 0.6f.
//   Cells with so <= 0.59999f: ex <= so*(1+2^-24) < 0.6f  => xthr=+INF (never captured).
__global__ __launch_bounds__(256) void decode_kernel(
        const float* __restrict__ p0, const float* __restrict__ p1,
        const float* __restrict__ p2,
        float4* __restrict__ boxes, float* __restrict__ so_arr,
        float* __restrict__ xthr_arr, DecParams dp) {
    int blk = blockIdx.x;
    int b = blk / 93;
    int rem = blk % 93;
    int a = rem / 31;
    int seg = rem % 31;
    int s, cellblk;
    if (seg < 23)      { s = 0; cellblk = seg; }
    else if (seg < 29) { s = 1; cellblk = seg - 23; }
    else               { s = 2; cellblk = seg - 29; }
    const int SS_[3]  = {76, 38, 19};
    const int HW_[3]  = {5776, 1444, 361};
    const int OFF_[3] = {0, 5776, 7220};
    const float* __restrict__ pr = (s == 0) ? p0 : (s == 1) ? p1 : p2;
    int S = SS_[s], HW = HW_[s];
    int cell = cellblk * 256 + (int)threadIdx.x;
    if (cell >= HW) return;
    const float* pb = pr + ((size_t)b * 255 + (size_t)a * 85) * (size_t)HW + cell;

    float tx  = pb[0];
    float ty  = pb[(size_t)HW];
    float tw  = pb[(size_t)2 * HW];
    float th  = pb[(size_t)3 * HW];
    float obj = pb[(size_t)4 * HW];

    float Sf = (float)S;
    float gx = (float)(cell % S);
    float gy = (float)(cell / S);
    float cx = (sigf(tx) + gx) / Sf;
    float cy = (sigf(ty) + gy) / Sf;
    float aw = dp.aw[s * 3 + a], ah = dp.ah[s * 3 + a];
    float bw = expf_cr(tw) * aw;
    float bh = expf_cr(th) * ah;
    float x1 = cx - 0.5f * bw;
    float y1 = cy - 0.5f * bh;
    int n = a * SUMHW + OFF_[s] + cell;
    boxes[(size_t)b * NN + n] = make_float4(x1, y1, x1 + bw, y1 + bh);

    float so = sigf(obj);
    size_t pidx = (size_t)b * PADNN + a * ASTRIDE + OFF_[s] + cell;
    so_arr[pidx] = so;
    float thr = __int_as_float(0x7F800000);       // +INF
    if (so > 0.59999f) {
        double arg = (double)so / 0.59999 - 1.0;
        thr = __double2float_rd(-log(arg));       // round DOWN: conservative capture
    }
    xthr_arr[pidx] = thr;
}

// ---------------- Stage B: dense stream + threshold scatter ----------------
// grid: 16 b * 3 a * 9 cellsegs(6 s0 + 2 s1 + 1 s2) * 4 classgroups = 1728 blocks
__global__ __launch_bounds__(256) void scatter_kernel(
        const float* __restrict__ p0, const float* __restrict__ p1,
        const float* __restrict__ p2,
        const float* __restrict__ xthr_arr,
        unsigned long long* __restrict__ glist, unsigned int* __restrict__ gcnt) {
    __shared__ unsigned long long stg[20][STAGECAP];   // 15360 B
    __shared__ unsigned int lcnt[20];
    __shared__ unsigned int lbase[20];

    int blk = blockIdx.x;
    int b = blk / 108;
    int rem = blk % 108;
    int a = rem / 36;
    int rem2 = rem % 36;
    int seg = rem2 / 4;
    int cg  = rem2 % 4;          // 20 classes per group
    int s, segi;
    if (seg < 6)      { s = 0; segi = seg; }
    else if (seg < 8) { s = 1; segi = seg - 6; }
    else              { s = 2; segi = 0; }
    const int HW_[3]  = {5776, 1444, 361};
    const int OFF_[3] = {0, 5776, 7220};
    const float* __restrict__ pr = (s == 0) ? p0 : (s == 1) ? p1 : p2;
    int HW = HW_[s], OFF = OFF_[s];
    int t = threadIdx.x;

    for (int i = t; i < 20; i += 256) lcnt[i] = 0;
    __syncthreads();

    int cell0 = segi * 1024 + t * 4;
    const float INF = __int_as_float(0x7F800000);
    float th0 = INF, th1 = INF, th2 = INF, th3 = INF;
    const float* xt = xthr_arr + (size_t)b * PADNN + a * ASTRIDE + OFF;
    // s0/s1 in-range threads are always 4-aligned & full (5776,656,1024,420 all %4==0)
    bool vec4 = (s != 2) && (cell0 + 3 < HW);
    if (vec4) {
        float4 tv = *(const float4*)(xt + cell0);
        th0 = tv.x; th1 = tv.y; th2 = tv.z; th3 = tv.w;
    } else {
        if (cell0     < HW) th0 = xt[cell0];
        if (cell0 + 1 < HW) th1 = xt[cell0 + 1];
        if (cell0 + 2 < HW) th2 = xt[cell0 + 2];
        if (cell0 + 3 < HW) th3 = xt[cell0 + 3];
    }
    int n0 = a * SUMHW + OFF + cell0;
    int cbase = cg * 20;
    int rowb = b * NCLS + cbase;

    auto push = [&](int g, float x, int n) {
        unsigned long long e =
            ((unsigned long long)__float_as_uint(x) << 32) | (unsigned)n;
        unsigned pos = atomicAdd(&lcnt[g], 1u);
        if (pos < STAGECAP) stg[g][pos] = e;
        else {                                   // ~never: direct global spill
            unsigned gp = atomicAdd(&gcnt[rowb + g], 1u);
            if (gp < GCAP) glist[(size_t)(rowb + g) * GCAP + gp] = e;
        }
    };

    if (cell0 < HW) {
#pragma unroll 2
        for (int g = 0; g < 20; ++g) {
            const float* __restrict__ cp =
                pr + ((size_t)b * 255 + (size_t)a * 85 + 5 + (size_t)(cbase + g)) * (size_t)HW;
            if (vec4) {
                float4 xv = *(const float4*)(cp + cell0);
                if (xv.x > th0) push(g, xv.x, n0);
                if (xv.y > th1) push(g, xv.y, n0 + 1);
                if (xv.z > th2) push(g, xv.z, n0 + 2);
                if (xv.w > th3) push(g, xv.w, n0 + 3);
            } else {
                float v0 = (cell0     < HW) ? cp[cell0]     : 0.0f;
                float v1 = (cell0 + 1 < HW) ? cp[cell0 + 1] : 0.0f;
                float v2 = (cell0 + 2 < HW) ? cp[cell0 + 2] : 0.0f;
                float v3 = (cell0 + 3 < HW) ? cp[cell0 + 3] : 0.0f;
                if (v0 > th0) push(g, v0, n0);
                if (v1 > th1) push(g, v1, n0 + 1);
                if (v2 > th2) push(g, v2, n0 + 2);
                if (v3 > th3) push(g, v3, n0 + 3);
            }
        }
    }
    __syncthreads();

    // flush: ONE global atomic per class, then coalesced copy
    if (t < 20) {
        unsigned m = lcnt[t]; if (m > STAGECAP) m = STAGECAP;
        lbase[t] = atomicAdd(&gcnt[rowb + t], m);
        lcnt[t] = m;
    }
    __syncthreads();
    for (int g = 0; g < 20; ++g) {
        unsigned m = lcnt[g], base = lbase[g];
        for (unsigned i = t; i < m; i += 256) {
            unsigned p = base + i;
            if (p < GCAP) glist[(size_t)(rowb + g) * GCAP + p] = stg[g][i];
        }
    }
}

// ------- Stage C: per-(b,c) exact rescore + top-K + greedy NMS -------
__global__ __launch_bounds__(256) void select_nms_kernel(
        const float* __restrict__ p0, const float* __restrict__ p1,
        const float* __restrict__ p2,
        const float* __restrict__ so_arr,
        const float4* __restrict__ boxes,
        const unsigned long long* __restrict__ glist,
        const unsigned int* __restrict__ gcnt,
        float* __restrict__ out) {
    __shared__ unsigned long long skey[GCAP];     // 16 KB
    __shared__ unsigned int hist[512];
    __shared__ unsigned int sums[256];
    __shared__ float bxs[TOPK][4];
    __shared__ float areas[TOPK];
    __shared__ float pvs[TOPK];
    __shared__ unsigned int sh_bin, sh_above, gcount;

    int t = threadIdx.x;
    int bid = blockIdx.x;          // b*80 + c
    int b = bid / NCLS;
    int c = bid % NCLS;
    const float4* brow = boxes + (size_t)b * NN;

    auto sortKeys = [&](unsigned Gc) {
        int M = TOPK;
        while ((unsigned)M < Gc) M <<= 1;          // <= GCAP
        for (int i = t; i < M; i += 256) if ((unsigned)i >= Gc) skey[i] = 0ULL;
        __syncthreads();
        for (int k = 2; k <= M; k <<= 1) {
            for (int j = k >> 1; j > 0; j >>= 1) {
                for (int i = t; i < M; i += 256) {
                    int l = i ^ j;
                    if (l > i) {
                        unsigned long long a0 = skey[i], a1 = skey[l];
                        bool sw = ((i & k) == 0) ? (a0 < a1) : (a0 > a1);
                        if (sw) { skey[i] = a1; skey[l] = a0; }
                    }
                }
                __syncthreads();
            }
        }
    };

    unsigned G = gcnt[bid];
    bool fb = (G > GCAP);
    unsigned Gc = 0;
    if (!fb) {
        const unsigned long long* gl = glist + (size_t)bid * GCAP;
        for (unsigned i = t; i < G; i += 256) {
            unsigned long long e = gl[i];
            unsigned xb = (unsigned)(e >> 32);
            unsigned n  = (unsigned)(e & 0xFFFFFFFFu);
            unsigned a  = n / SUMHW;
            unsigned r  = n - a * SUMHW;
            float so = so_arr[(size_t)b * PADNN + a * ASTRIDE + r];
            float ex = so * sigf(__uint_as_float(xb));   // reference-identical chain
            skey[i] = (ex > 0.3f)
                ? (((unsigned long long)__float_as_uint(ex) << 32) | (unsigned)(~n))
                : 0ULL;
        }
        Gc = G;
        sortKeys(Gc);
        // success <=> kept 128th has ex >= 0.6f; every missed element is < 0.6f strictly
        bool ok = (Gc >= TOPK) && ((unsigned)(skey[TOPK - 1] >> 32) >= SBITS);
        if (!ok) fb = true;
    }

    if (fb) {
        // ---- full re-scan fallback (rounds 3/4 validated); never taken on bench data ----
        auto scanScalar = [&](auto&& body) {
#pragma unroll
            for (int s = 0; s < 3; ++s) {
                const float* __restrict__ pr = (s == 0) ? p0 : (s == 1) ? p1 : p2;
                const int HW  = (s == 0) ? 5776 : (s == 1) ? 1444 : 361;
                const int OFF = (s == 0) ? 0 : (s == 1) ? 5776 : 7220;
#pragma unroll
                for (int a = 0; a < 3; ++a) {
                    const float* __restrict__ cp =
                        pr + ((size_t)b * 255 + (size_t)a * 85 + 5 + (size_t)c) * (size_t)HW;
                    const float* __restrict__ sop =
                        so_arr + (size_t)b * PADNN + a * ASTRIDE + OFF;
                    int n0 = a * SUMHW + OFF;
                    for (int i = t; i < HW; i += 256) {
                        float so = sop[i];
                        if (so <= 0.2999f) continue;
                        float x = cp[i];
                        float st = 1.0f / (1.0f + __expf(-x));
                        float sca = st * so;
                        if (sca > 0.2999f) body(sca, x, so, n0 + i);
                    }
                }
            }
        };
        for (int i = t; i < 512; i += 256) hist[i] = 0;
        if (t == 0) gcount = 0;
        __syncthreads();
        scanScalar([&](float sca, float, float, int) {
            unsigned bin = (__float_as_uint(sca) - KEYBASE) >> 15;
            if (bin > 511u) bin = 511u;
            atomicAdd(&hist[bin], 1u);
        });
        __syncthreads();
        unsigned m0 = hist[2 * t], m1 = hist[2 * t + 1];
        sums[t] = m0 + m1;
        __syncthreads();
        for (int d = 1; d < 256; d <<= 1) {
            unsigned v = sums[t];
            if (t + d < 256) v += sums[t + d];
            __syncthreads();
            sums[t] = v;
            __syncthreads();
        }
        unsigned total = sums[0];
        bool gatherAll = (total < TOPK);
        unsigned gth = 0;
        if (!gatherAll) {
            unsigned si = sums[t], se = si - (m0 + m1);
            if (se < TOPK && TOPK <= si) {
                if (TOPK <= se + m1) { sh_bin = 2 * t + 1; sh_above = se; }
                else                 { sh_bin = 2 * t;     sh_above = se + m1; }
            }
            __syncthreads();
            unsigned B1 = sh_bin, above1 = sh_above;
            unsigned cntB = hist[B1];
            unsigned binlo = KEYBASE + (B1 << 15);
            __syncthreads();
            if (above1 + cntB <= 768) {
                gth = binlo - 256;              // 256-ulp margin >> approx err (r3-validated)
            } else {
                if (t < 256) hist[t] = 0;
                __syncthreads();
                scanScalar([&](float sca, float, float, int) {
                    unsigned key = __float_as_uint(sca);
                    if (((key - KEYBASE) >> 15) == B1) {
                        unsigned sub = (key - binlo) >> 7;
                        if (sub > 255u) sub = 255u;
                        atomicAdd(&hist[sub], 1u);
                    }
                });
                __syncthreads();
                unsigned R2 = TOPK - above1;
                unsigned sl = hist[t];
                sums[t] = sl;
                __syncthreads();
                for (int d = 1; d < 256; d <<= 1) {
                    unsigned v = sums[t];
                    if (t + d < 256) v += sums[t + d];
                    __syncthreads();
                    sums[t] = v;
                    __syncthreads();
                }
                unsigned si2 = sums[t], se2 = si2 - sl;
                if (se2 < R2 && R2 <= si2) sh_bin = (unsigned)t;
                __syncthreads();
                gth = binlo + (sh_bin << 7) - 256;
            }
        }
        __syncthreads();
        scanScalar([&](float sca, float x, float so, int n) {
            unsigned key = __float_as_uint(sca);
            if (gatherAll || key >= gth) {
                unsigned pos = atomicAdd(&gcount, 1u);
                if (pos < CAP) {
                    float ex = so * sigf(x);
                    skey[pos] = (ex > 0.3f)
                        ? (((unsigned long long)__float_as_uint(ex) << 32) |
                           (unsigned)(~(unsigned)n))
                        : 0ULL;
                }
            }
        });
        __syncthreads();
        Gc = gcount < CAP ? gcount : CAP;
        sortKeys(Gc);
    }

    // --- extract top-128 ---
    if (t < TOPK) {
        bool vld = ((unsigned)t < Gc) && (skey[t] != 0ULL);
        unsigned long long e = vld ? skey[t] : 0ULL;
        float sc = __uint_as_float((unsigned)(e >> 32));
        unsigned n = ~(unsigned)(e & 0xFFFFFFFFu);
        float4 bb = make_float4(0.f, 0.f, 0.f, 0.f);
        if (vld) bb = brow[n];
        bxs[t][0] = bb.x; bxs[t][1] = bb.y; bxs[t][2] = bb.z; bxs[t][3] = bb.w;
        areas[t] = (bb.z - bb.x) * (bb.w - bb.y);
        pvs[t] = vld ? sc : -1.0f;
    }
    __syncthreads();

    // --- greedy NMS: wave-synchronous, zero barriers in the loop ---
    if (t < 64) {
        float pv0 = pvs[t],        pv1 = pvs[t + 64];
        float x10 = bxs[t][0],     y10 = bxs[t][1],     x20 = bxs[t][2],     y20 = bxs[t][3];
        float x11 = bxs[t+64][0],  y11 = bxs[t+64][1],  x21 = bxs[t+64][2],  y21 = bxs[t+64][3];
        float a0 = areas[t], a1 = areas[t + 64];
        for (int i = 0; i < TOPK; ++i) {
            bool hi = i >= 64; int src = i & 63;
            float pi = __shfl(hi ? pv1 : pv0, src);
            if (pi > 0.0f) {                       // wave-uniform
                float xi1 = __shfl(hi ? x11 : x10, src);
                float yi1 = __shfl(hi ? y11 : y10, src);
                float xi2 = __shfl(hi ? x21 : x20, src);
                float yi2 = __shfl(hi ? y21 : y20, src);
                float ai  = __shfl(hi ? a1  : a0,  src);
                if (t > i) {
                    float xx1 = fmaxf(xi1, x10), yy1 = fmaxf(yi1, y10);
                    float xx2 = fminf(xi2, x20), yy2 = fminf(yi2, y20);
                    float ww = fmaxf(xx2 - xx1, 0.0f), hh = fmaxf(yy2 - yy1, 0.0f);
                    float inter = ww * hh;
                    float iou = inter / (ai + a0 - inter);
                    if (iou > 0.45f) pv0 = -1.0f;
                }
                if (t + 64 > i) {
                    float xx1 = fmaxf(xi1, x11), yy1 = fmaxf(yi1, y11);
                    float xx2 = fminf(xi2, x21), yy2 = fminf(yi2, y21);
                    float ww = fmaxf(xx2 - xx1, 0.0f), hh = fmaxf(yy2 - yy1, 0.0f);
                    float inter = ww * hh;
                    float iou = inter / (ai + a1 - inter);
                    if (iou > 0.45f) pv1 = -1.0f;
                }
            }
        }
        pvs[t] = pv0; pvs[t + 64] = pv1;
    }
    __syncthreads();

    // --- write [K,6] = x1,y1,x2,y2,score,class ---
    float* o = out + (size_t)bid * TOPK * 6;
    for (int i = t; i < TOPK; i += 256) {
        bool kept = pvs[i] > 0.0f;
        o[i * 6 + 0] = kept ? bxs[i][0] : 0.0f;
        o[i * 6 + 1] = kept ? bxs[i][1] : 0.0f;
        o[i * 6 + 2] = kept ? bxs[i][2] : 0.0f;
        o[i * 6 + 3] = kept ? bxs[i][3] : 0.0f;
        o[i * 6 + 4] = kept ? pvs[i] : 0.0f;
        o[i * 6 + 5] = (float)c;
    }
}

extern "C" void kernel_launch(void* const* d_in, const int* in_sizes, int n_in,
                              void* d_out, int out_size, void* d_ws, size_t ws_size,
                              hipStream_t stream) {
    const float* p0 = (const float*)d_in[0];
    const float* p1 = (const float*)d_in[1];
    const float* p2 = (const float*)d_in[2];
    float* out = (float*)d_out;

    char* ws = (char*)d_ws;
    unsigned int* gcnt = (unsigned int*)ws;                        // 5120 B (pad 8192)
    float4* boxes = (float4*)(ws + 8192);                          // 5,822,208 B
    float*  so_arr  = (float*)(ws + 5830400ull);                   // 1,456,128 B
    float*  xthr    = (float*)(ws + 7286528ull);                   // 1,456,128 B
    unsigned long long* glist = (unsigned long long*)(ws + 8742656ull); // 20,971,520 B

    static const float ANC[3][3][2] = {
        {{12, 16}, {19, 36}, {40, 28}},
        {{36, 75}, {76, 55}, {72, 146}},
        {{142, 110}, {192, 243}, {459, 401}},
    };
    static const int RED[3] = {8, 16, 32};
    static const int SS[3]  = {76, 38, 19};

    DecParams dp;
    for (int s = 0; s < 3; ++s)
        for (int a = 0; a < 3; ++a) {
            float Sf = (float)SS[s];
            dp.aw[s * 3 + a] = (ANC[s][a][0] / (float)RED[s]) / Sf;  // same f32 chain as ref
            dp.ah[s * 3 + a] = (ANC[s][a][1] / (float)RED[s]) / Sf;
        }

    hipMemsetAsync(gcnt, 0, BATCH * NCLS * sizeof(unsigned int), stream);
    decode_kernel<<<BATCH * 93, 256, 0, stream>>>(p0, p1, p2, boxes, so_arr, xthr, dp);
    scatter_kernel<<<1728, 256, 0, stream>>>(p0, p1, p2, xthr, glist, gcnt);
    select_nms_kernel<<<BATCH * NCLS, 256, 0, stream>>>(p0, p1, p2, so_arr, boxes,
                                                        glist, gcnt, out);
}

// Round 6
// 122.199 us; speedup vs baseline: 1.0561x; 1.0561x over previous
//
#include <hip/hip_runtime.h>
#include <math.h>

#define BATCH 16
#define NCLS 80
#define SUMHW 7581            // 76*76 + 38*38 + 19*19
#define NN 22743              // 3 anchors * SUMHW
#define ASTRIDE 7584          // padded per-anchor stride for so/xthr (7581 -> 7584, /4)
#define PADNN (3 * ASTRIDE)   // 22752
#define TOPK 128
#define CAP 1024              // fallback gather cap
#define GCAP 2048             // per-(b,c) global candidate list capacity (mean ~650)
#define STAGECAP 96           // per-class LDS staging cap in scatter
#define PRUNECAP 512          // post-prune survivor cap in select
#define KEYBASE 0x3E800000u   // bits of 0.25f (fallback histogram base)
#define KB2     0x3F180000u   // bits of 0.59375f (prune histogram base)
#define SBITS   0x3F19999Au   // bits of 0.6f

// exact sigmoid matching numpy f32 chain: correctly-rounded exp (double) -> f32 ops
__device__ __forceinline__ float sigf(float x) {
    float e = (float)exp(-(double)x);
    return 1.0f / (1.0f + e);
}
__device__ __forceinline__ float expf_cr(float x) {
    return (float)exp((double)x);
}

struct DecParams { float aw[9]; float ah[9]; };

// ---------------- Stage A: decode boxes + exact objectness + x-threshold ----------------
// xthr correctness (r5-validated):
//   Tp = 0.59999 (< 0.6f).  thr = -log(so/Tp - 1)  =>  sigmoid(thr) = Tp/so.
//   ex >= 0.6f  =>  x > thr (captured).   x <= thr  =>  ex < 0.6f (safe to miss).
//   so <= 0.59999f  =>  ex < 0.6f  =>  xthr=+INF.
__global__ __launch_bounds__(256) void decode_kernel(
        const float* __restrict__ p0, const float* __restrict__ p1,
        const float* __restrict__ p2,
        float4* __restrict__ boxes, float* __restrict__ so_arr,
        float* __restrict__ xthr_arr, DecParams dp) {
    int blk = blockIdx.x;
    int b = blk / 93;
    int rem = blk % 93;
    int a = rem / 31;
    int seg = rem % 31;
    int s, cellblk;
    if (seg < 23)      { s = 0; cellblk = seg; }
    else if (seg < 29) { s = 1; cellblk = seg - 23; }
    else               { s = 2; cellblk = seg - 29; }
    const int SS_[3]  = {76, 38, 19};
    const int HW_[3]  = {5776, 1444, 361};
    const int OFF_[3] = {0, 5776, 7220};
    const float* __restrict__ pr = (s == 0) ? p0 : (s == 1) ? p1 : p2;
    int S = SS_[s], HW = HW_[s];
    int cell = cellblk * 256 + (int)threadIdx.x;
    if (cell >= HW) return;
    const float* pb = pr + ((size_t)b * 255 + (size_t)a * 85) * (size_t)HW + cell;

    float tx  = pb[0];
    float ty  = pb[(size_t)HW];
    float tw  = pb[(size_t)2 * HW];
    float th  = pb[(size_t)3 * HW];
    float obj = pb[(size_t)4 * HW];

    float Sf = (float)S;
    float gx = (float)(cell % S);
    float gy = (float)(cell / S);
    float cx = (sigf(tx) + gx) / Sf;
    float cy = (sigf(ty) + gy) / Sf;
    float aw = dp.aw[s * 3 + a], ah = dp.ah[s * 3 + a];
    float bw = expf_cr(tw) * aw;
    float bh = expf_cr(th) * ah;
    float x1 = cx - 0.5f * bw;
    float y1 = cy - 0.5f * bh;
    int n = a * SUMHW + OFF_[s] + cell;
    boxes[(size_t)b * NN + n] = make_float4(x1, y1, x1 + bw, y1 + bh);

    float so = sigf(obj);
    size_t pidx = (size_t)b * PADNN + a * ASTRIDE + OFF_[s] + cell;
    so_arr[pidx] = so;
    float thr = __int_as_float(0x7F800000);       // +INF
    if (so > 0.59999f) {
        double arg = (double)so / 0.59999 - 1.0;
        thr = __double2float_rd(-log(arg));       // round DOWN: conservative capture
    }
    xthr_arr[pidx] = thr;
}

// ---------------- Stage B: dense stream + threshold scatter (approx key + payload) ----------------
// grid: 16 b * 3 a * 9 cellsegs(6 s0 + 2 s1 + 1 s2) * 4 classgroups = 1728 blocks
__global__ __launch_bounds__(256) void scatter_kernel(
        const float* __restrict__ p0, const float* __restrict__ p1,
        const float* __restrict__ p2,
        const float* __restrict__ so_arr, const float* __restrict__ xthr_arr,
        unsigned int* __restrict__ klist, unsigned long long* __restrict__ vlist,
        unsigned int* __restrict__ gcnt) {
    __shared__ unsigned int       skeys[20][STAGECAP];   // 7680 B
    __shared__ unsigned long long svals[20][STAGECAP];   // 15360 B
    __shared__ unsigned int lcnt[20];
    __shared__ unsigned int lbase[20];

    int blk = blockIdx.x;
    int b = blk / 108;
    int rem = blk % 108;
    int a = rem / 36;
    int rem2 = rem % 36;
    int seg = rem2 / 4;
    int cg  = rem2 % 4;          // 20 classes per group
    int s, segi;
    if (seg < 6)      { s = 0; segi = seg; }
    else if (seg < 8) { s = 1; segi = seg - 6; }
    else              { s = 2; segi = 0; }
    const int HW_[3]  = {5776, 1444, 361};
    const int OFF_[3] = {0, 5776, 7220};
    const float* __restrict__ pr = (s == 0) ? p0 : (s == 1) ? p1 : p2;
    int HW = HW_[s], OFF = OFF_[s];
    int t = threadIdx.x;

    for (int i = t; i < 20; i += 256) lcnt[i] = 0;
    __syncthreads();

    int cell0 = segi * 1024 + t * 4;
    const float INF = __int_as_float(0x7F800000);
    float th0 = INF, th1 = INF, th2 = INF, th3 = INF;
    float so0 = 0.f, so1 = 0.f, so2 = 0.f, so3 = 0.f;
    const float* xt = xthr_arr + (size_t)b * PADNN + a * ASTRIDE + OFF;
    const float* sp = so_arr   + (size_t)b * PADNN + a * ASTRIDE + OFF;
    bool vec4 = (s != 2) && (cell0 + 3 < HW);
    if (vec4) {
        float4 tv = *(const float4*)(xt + cell0);
        float4 sv = *(const float4*)(sp + cell0);
        th0 = tv.x; th1 = tv.y; th2 = tv.z; th3 = tv.w;
        so0 = sv.x; so1 = sv.y; so2 = sv.z; so3 = sv.w;
    } else {
        if (cell0     < HW) { th0 = xt[cell0];     so0 = sp[cell0]; }
        if (cell0 + 1 < HW) { th1 = xt[cell0 + 1]; so1 = sp[cell0 + 1]; }
        if (cell0 + 2 < HW) { th2 = xt[cell0 + 2]; so2 = sp[cell0 + 2]; }
        if (cell0 + 3 < HW) { th3 = xt[cell0 + 3]; so3 = sp[cell0 + 3]; }
    }
    int n0 = a * SUMHW + OFF + cell0;
    int cbase = cg * 20;
    int rowb = b * NCLS + cbase;

    auto push = [&](int g, float x, float so, int n) {
        float st = 1.0f / (1.0f + __expf(-x));   // approx sigmoid, err few ulp
        unsigned key = __float_as_uint(st * so);
        unsigned long long val =
            ((unsigned long long)__float_as_uint(x) << 32) | (unsigned)n;
        unsigned pos = atomicAdd(&lcnt[g], 1u);
        if (pos < STAGECAP) { skeys[g][pos] = key; svals[g][pos] = val; }
        else {                                   // ~never: direct global spill
            unsigned gp = atomicAdd(&gcnt[rowb + g], 1u);
            if (gp < GCAP) {
                klist[(size_t)(rowb + g) * GCAP + gp] = key;
                vlist[(size_t)(rowb + g) * GCAP + gp] = val;
            }
        }
    };

    if (cell0 < HW) {
#pragma unroll 2
        for (int g = 0; g < 20; ++g) {
            const float* __restrict__ cp =
                pr + ((size_t)b * 255 + (size_t)a * 85 + 5 + (size_t)(cbase + g)) * (size_t)HW;
            if (vec4) {
                float4 xv = *(const float4*)(cp + cell0);
                if (xv.x > th0) push(g, xv.x, so0, n0);
                if (xv.y > th1) push(g, xv.y, so1, n0 + 1);
                if (xv.z > th2) push(g, xv.z, so2, n0 + 2);
                if (xv.w > th3) push(g, xv.w, so3, n0 + 3);
            } else {
                float v0 = (cell0     < HW) ? cp[cell0]     : 0.0f;
                float v1 = (cell0 + 1 < HW) ? cp[cell0 + 1] : 0.0f;
                float v2 = (cell0 + 2 < HW) ? cp[cell0 + 2] : 0.0f;
                float v3 = (cell0 + 3 < HW) ? cp[cell0 + 3] : 0.0f;
                if (v0 > th0) push(g, v0, so0, n0);
                if (v1 > th1) push(g, v1, so1, n0 + 1);
                if (v2 > th2) push(g, v2, so2, n0 + 2);
                if (v3 > th3) push(g, v3, so3, n0 + 3);
            }
        }
    }
    __syncthreads();

    // flush: ONE global atomic per class, then coalesced copy
    if (t < 20) {
        unsigned m = lcnt[t]; if (m > STAGECAP) m = STAGECAP;
        lbase[t] = atomicAdd(&gcnt[rowb + t], m);
        lcnt[t] = m;
    }
    __syncthreads();
    for (int g = 0; g < 20; ++g) {
        unsigned m = lcnt[g], base = lbase[g];
        for (unsigned i = t; i < m; i += 256) {
            unsigned p = base + i;
            if (p < GCAP) {
                klist[(size_t)(rowb + g) * GCAP + p] = skeys[g][i];
                vlist[(size_t)(rowb + g) * GCAP + p] = svals[g][i];
            }
        }
    }
}

// ------- Stage C: per-(b,c) histogram-prune + exact rescore + top-K + greedy NMS -------
__global__ __launch_bounds__(256) void select_nms_kernel(
        const float* __restrict__ p0, const float* __restrict__ p1,
        const float* __restrict__ p2,
        const float* __restrict__ so_arr,
        const float4* __restrict__ boxes,
        const unsigned int* __restrict__ klist,
        const unsigned long long* __restrict__ vlist,
        const unsigned int* __restrict__ gcnt,
        float* __restrict__ out) {
    __shared__ unsigned long long skey[CAP];      // 8 KB (fallback needs 1024)
    __shared__ unsigned int hist[512];
    __shared__ unsigned int sums[256];
    __shared__ float bxs[TOPK][4];
    __shared__ float areas[TOPK];
    __shared__ float pvs[TOPK];
    __shared__ unsigned int sh_bin, sh_above, gcount;

    int t = threadIdx.x;
    int bid = blockIdx.x;          // b*80 + c
    int b = bid / NCLS;
    int c = bid % NCLS;
    const float4* brow = boxes + (size_t)b * NN;

    auto sortKeys = [&](unsigned Gc) {
        int M = TOPK;
        while ((unsigned)M < Gc) M <<= 1;          // <= CAP
        for (int i = t; i < M; i += 256) if ((unsigned)i >= Gc) skey[i] = 0ULL;
        __syncthreads();
        for (int k = 2; k <= M; k <<= 1) {
            for (int j = k >> 1; j > 0; j >>= 1) {
                for (int i = t; i < M; i += 256) {
                    int l = i ^ j;
                    if (l > i) {
                        unsigned long long a0 = skey[i], a1 = skey[l];
                        bool sw = ((i & k) == 0) ? (a0 < a1) : (a0 > a1);
                        if (sw) { skey[i] = a1; skey[l] = a0; }
                    }
                }
                __syncthreads();
            }
        }
    };

    unsigned G = gcnt[bid];
    // G < TOPK => true top-128 needs sub-0.6 elements the scatter never captured
    bool fb = (G > GCAP) || (G < TOPK);
    unsigned Gc = 0;
    if (!fb) {
        const unsigned int* kl = klist + (size_t)bid * GCAP;
        for (int i = t; i < 512; i += 256) hist[i] = 0;
        if (t == 0) gcount = 0;
        __syncthreads();
        // --- pass 1: 512-bin histogram of stored approx keys (16384-ulp bins) ---
        for (unsigned i = t; i < G; i += 256) {
            unsigned bin = (kl[i] - KB2) >> 14;
            if (bin > 511u) bin = 511u;
            atomicAdd(&hist[bin], 1u);
        }
        __syncthreads();
        unsigned m0 = hist[2 * t], m1 = hist[2 * t + 1];
        sums[t] = m0 + m1;
        __syncthreads();
        for (int d = 1; d < 256; d <<= 1) {
            unsigned v = sums[t];
            if (t + d < 256) v += sums[t + d];
            __syncthreads();
            sums[t] = v;
            __syncthreads();
        }
        unsigned si = sums[t], se = si - (m0 + m1);
        if (se < TOPK && TOPK <= si) {              // unique crossing thread
            if (TOPK <= se + m1) { sh_bin = 2 * t + 1; sh_above = se; }
            else                 { sh_bin = 2 * t;     sh_above = se + m1; }
        }
        __syncthreads();
        unsigned B1 = sh_bin, above1 = sh_above;
        unsigned cntB = hist[B1];
        unsigned binlo = KB2 + (B1 << 14);
        if (above1 + cntB > PRUNECAP - 64) {
            fb = true;                               // fat bin (~never): full re-scan
        } else {
            // --- pass 2: gather keys >= binlo - 256ulp (r3-validated margin),
            //             exact-rescore survivors only ---
            unsigned gth = binlo - 256;
            for (unsigned i = t; i < G; i += 256) {
                if (kl[i] >= gth) {
                    unsigned pos = atomicAdd(&gcount, 1u);
                    if (pos < PRUNECAP) {
                        unsigned long long v = vlist[(size_t)bid * GCAP + i];
                        unsigned xb = (unsigned)(v >> 32);
                        unsigned n  = (unsigned)(v & 0xFFFFFFFFu);
                        unsigned a  = n / SUMHW;
                        unsigned r  = n - a * SUMHW;
                        float so = so_arr[(size_t)b * PADNN + a * ASTRIDE + r];
                        float ex = so * sigf(__uint_as_float(xb));   // ref-identical chain
                        skey[pos] = (ex > 0.3f)
                            ? (((unsigned long long)__float_as_uint(ex) << 32) |
                               (unsigned)(~n))
                            : 0ULL;
                    }
                }
            }
            __syncthreads();
            if (gcount > PRUNECAP) fb = true;        // overflow (~never): full re-scan
            Gc = gcount < PRUNECAP ? gcount : PRUNECAP;
            if (!fb) {
                sortKeys(Gc);
                // success <=> kept 128th has ex >= 0.6f (every scatter-missed elem < 0.6f)
                bool ok = (Gc >= TOPK) && ((unsigned)(skey[TOPK - 1] >> 32) >= SBITS);
                if (!ok) fb = true;
            }
        }
    }

    if (fb) {
        // ---- full re-scan fallback (rounds 3/4 validated); never taken on bench data ----
        auto scanScalar = [&](auto&& body) {
#pragma unroll
            for (int s = 0; s < 3; ++s) {
                const float* __restrict__ pr = (s == 0) ? p0 : (s == 1) ? p1 : p2;
                const int HW  = (s == 0) ? 5776 : (s == 1) ? 1444 : 361;
                const int OFF = (s == 0) ? 0 : (s == 1) ? 5776 : 7220;
#pragma unroll
                for (int a = 0; a < 3; ++a) {
                    const float* __restrict__ cp =
                        pr + ((size_t)b * 255 + (size_t)a * 85 + 5 + (size_t)c) * (size_t)HW;
                    const float* __restrict__ sop =
                        so_arr + (size_t)b * PADNN + a * ASTRIDE + OFF;
                    int n0 = a * SUMHW + OFF;
                    for (int i = t; i < HW; i += 256) {
                        float so = sop[i];
                        if (so <= 0.2999f) continue;
                        float x = cp[i];
                        float st = 1.0f / (1.0f + __expf(-x));
                        float sca = st * so;
                        if (sca > 0.2999f) body(sca, x, so, n0 + i);
                    }
                }
            }
        };
        __syncthreads();
        for (int i = t; i < 512; i += 256) hist[i] = 0;
        if (t == 0) gcount = 0;
        __syncthreads();
        scanScalar([&](float sca, float, float, int) {
            unsigned bin = (__float_as_uint(sca) - KEYBASE) >> 15;
            if (bin > 511u) bin = 511u;
            atomicAdd(&hist[bin], 1u);
        });
        __syncthreads();
        unsigned m0 = hist[2 * t], m1 = hist[2 * t + 1];
        sums[t] = m0 + m1;
        __syncthreads();
        for (int d = 1; d < 256; d <<= 1) {
            unsigned v = sums[t];
            if (t + d < 256) v += sums[t + d];
            __syncthreads();
            sums[t] = v;
            __syncthreads();
        }
        unsigned total = sums[0];
        bool gatherAll = (total < TOPK);
        unsigned gth = 0;
        if (!gatherAll) {
            unsigned si = sums[t], se = si - (m0 + m1);
            if (se < TOPK && TOPK <= si) {
                if (TOPK <= se + m1) { sh_bin = 2 * t + 1; sh_above = se; }
                else                 { sh_bin = 2 * t;     sh_above = se + m1; }
            }
            __syncthreads();
            unsigned B1 = sh_bin, above1 = sh_above;
            unsigned cntB = hist[B1];
            unsigned binlo = KEYBASE + (B1 << 15);
            __syncthreads();
            if (above1 + cntB <= 768) {
                gth = binlo - 256;              // 256-ulp margin >> approx err (r3-validated)
            } else {
                if (t < 256) hist[t] = 0;
                __syncthreads();
                scanScalar([&](float sca, float, float, int) {
                    unsigned key = __float_as_uint(sca);
                    if (((key - KEYBASE) >> 15) == B1) {
                        unsigned sub = (key - binlo) >> 7;
                        if (sub > 255u) sub = 255u;
                        atomicAdd(&hist[sub], 1u);
                    }
                });
                __syncthreads();
                unsigned R2 = TOPK - above1;
                unsigned sl = hist[t];
                sums[t] = sl;
                __syncthreads();
                for (int d = 1; d < 256; d <<= 1) {
                    unsigned v = sums[t];
                    if (t + d < 256) v += sums[t + d];
                    __syncthreads();
                    sums[t] = v;
                    __syncthreads();
                }
                unsigned si2 = sums[t], se2 = si2 - sl;
                if (se2 < R2 && R2 <= si2) sh_bin = (unsigned)t;
                __syncthreads();
                gth = binlo + (sh_bin << 7) - 256;
            }
        }
        __syncthreads();
        scanScalar([&](float sca, float x, float so, int n) {
            unsigned key = __float_as_uint(sca);
            if (gatherAll || key >= gth) {
                unsigned pos = atomicAdd(&gcount, 1u);
                if (pos < CAP) {
                    float ex = so * sigf(x);
                    skey[pos] = (ex > 0.3f)
                        ? (((unsigned long long)__float_as_uint(ex) << 32) |
                           (unsigned)(~(unsigned)n))
                        : 0ULL;
                }
            }
        });
        __syncthreads();
        Gc = gcount < CAP ? gcount : CAP;
        sortKeys(Gc);
    }

    // --- extract top-128 ---
    if (t < TOPK) {
        bool vld = ((unsigned)t < Gc) && (skey[t] != 0ULL);
        unsigned long long e = vld ? skey[t] : 0ULL;
        float sc = __uint_as_float((unsigned)(e >> 32));
        unsigned n = ~(unsigned)(e & 0xFFFFFFFFu);
        float4 bb = make_float4(0.f, 0.f, 0.f, 0.f);
        if (vld) bb = brow[n];
        bxs[t][0] = bb.x; bxs[t][1] = bb.y; bxs[t][2] = bb.z; bxs[t][3] = bb.w;
        areas[t] = (bb.z - bb.x) * (bb.w - bb.y);
        pvs[t] = vld ? sc : -1.0f;
    }
    __syncthreads();

    // --- greedy NMS: wave-synchronous, zero barriers in the loop ---
    if (t < 64) {
        float pv0 = pvs[t],        pv1 = pvs[t + 64];
        float x10 = bxs[t][0],     y10 = bxs[t][1],     x20 = bxs[t][2],     y20 = bxs[t][3];
        float x11 = bxs[t+64][0],  y11 = bxs[t+64][1],  x21 = bxs[t+64][2],  y21 = bxs[t+64][3];
        float a0 = areas[t], a1 = areas[t + 64];
        for (int i = 0; i < TOPK; ++i) {
            bool hi = i >= 64; int src = i & 63;
            float pi = __shfl(hi ? pv1 : pv0, src);
            if (pi > 0.0f) {                       // wave-uniform
                float xi1 = __shfl(hi ? x11 : x10, src);
                float yi1 = __shfl(hi ? y11 : y10, src);
                float xi2 = __shfl(hi ? x21 : x20, src);
                float yi2 = __shfl(hi ? y21 : y20, src);
                float ai  = __shfl(hi ? a1  : a0,  src);
                if (t > i) {
                    float xx1 = fmaxf(xi1, x10), yy1 = fmaxf(yi1, y10);
                    float xx2 = fminf(xi2, x20), yy2 = fminf(yi2, y20);
                    float ww = fmaxf(xx2 - xx1, 0.0f), hh = fmaxf(yy2 - yy1, 0.0f);
                    float inter = ww * hh;
                    float iou = inter / (ai + a0 - inter);
                    if (iou > 0.45f) pv0 = -1.0f;
                }
                if (t + 64 > i) {
                    float xx1 = fmaxf(xi1, x11), yy1 = fmaxf(yi1, y11);
                    float xx2 = fminf(xi2, x21), yy2 = fminf(yi2, y21);
                    float ww = fmaxf(xx2 - xx1, 0.0f), hh = fmaxf(yy2 - yy1, 0.0f);
                    float inter = ww * hh;
                    float iou = inter / (ai + a1 - inter);
                    if (iou > 0.45f) pv1 = -1.0f;
                }
            }
        }
        pvs[t] = pv0; pvs[t + 64] = pv1;
    }
    __syncthreads();

    // --- write [K,6] = x1,y1,x2,y2,score,class ---
    float* o = out + (size_t)bid * TOPK * 6;
    for (int i = t; i < TOPK; i += 256) {
        bool kept = pvs[i] > 0.0f;
        o[i * 6 + 0] = kept ? bxs[i][0] : 0.0f;
        o[i * 6 + 1] = kept ? bxs[i][1] : 0.0f;
        o[i * 6 + 2] = kept ? bxs[i][2] : 0.0f;
        o[i * 6 + 3] = kept ? bxs[i][3] : 0.0f;
        o[i * 6 + 4] = kept ? pvs[i] : 0.0f;
        o[i * 6 + 5] = (float)c;
    }
}

extern "C" void kernel_launch(void* const* d_in, const int* in_sizes, int n_in,
                              void* d_out, int out_size, void* d_ws, size_t ws_size,
                              hipStream_t stream) {
    const float* p0 = (const float*)d_in[0];
    const float* p1 = (const float*)d_in[1];
    const float* p2 = (const float*)d_in[2];
    float* out = (float*)d_out;

    char* ws = (char*)d_ws;
    unsigned int* gcnt = (unsigned int*)ws;                        // 5120 B (pad 8192)
    float4* boxes = (float4*)(ws + 8192);                          // 5,822,208 B
    float*  so_arr  = (float*)(ws + 5830400ull);                   // 1,456,128 B
    float*  xthr    = (float*)(ws + 7286528ull);                   // 1,456,128 B
    unsigned int* klist = (unsigned int*)(ws + 8742656ull);        // 10,485,760 B
    unsigned long long* vlist = (unsigned long long*)(ws + 19228416ull); // 20,971,520 B

    static const float ANC[3][3][2] = {
        {{12, 16}, {19, 36}, {40, 28}},
        {{36, 75}, {76, 55}, {72, 146}},
        {{142, 110}, {192, 243}, {459, 401}},
    };
    static const int RED[3] = {8, 16, 32};
    static const int SS[3]  = {76, 38, 19};

    DecParams dp;
    for (int s = 0; s < 3; ++s)
        for (int a = 0; a < 3; ++a) {
            float Sf = (float)SS[s];
            dp.aw[s * 3 + a] = (ANC[s][a][0] / (float)RED[s]) / Sf;  // same f32 chain as ref
            dp.ah[s * 3 + a] = (ANC[s][a][1] / (float)RED[s]) / Sf;
        }

    hipMemsetAsync(gcnt, 0, BATCH * NCLS * sizeof(unsigned int), stream);
    decode_kernel<<<BATCH * 93, 256, 0, stream>>>(p0, p1, p2, boxes, so_arr, xthr, dp);
    scatter_kernel<<<1728, 256, 0, stream>>>(p0, p1, p2, so_arr, xthr, klist, vlist, gcnt);
    select_nms_kernel<<<BATCH * NCLS, 256, 0, stream>>>(p0, p1, p2, so_arr, boxes,
                                                        klist, vlist, gcnt, out);
}

// Round 7
// 98.661 us; speedup vs baseline: 1.3080x; 1.2386x over previous
//
#include <hip/hip_runtime.h>
#include <math.h>

#define BATCH 16
#define NCLS 80
#define SUMHW 7581            // 76*76 + 38*38 + 19*19
#define NN 22743              // 3 anchors * SUMHW
#define ASTRIDE 7584          // padded per-anchor stride for so/xthr (7581 -> 7584, /4)
#define PADNN (3 * ASTRIDE)   // 22752
#define TOPK 128
#define CAP 1024              // fallback gather cap
#define GCAP 2048             // per-(b,c) global candidate list capacity (mean ~670)
#define STAGECAP 96           // per-class LDS staging cap in scatter
#define PRUNECAP 512          // post-prune survivor cap in select
#define KEYBASE 0x3E800000u   // bits of 0.25f (fallback histogram base)
#define KB2     0x3F180000u   // bits of 0.59375f (prune histogram base)
#define SBITS   0x3F19999Au   // bits of 0.6f

// exact sigmoid matching numpy f32 chain: correctly-rounded exp (double) -> f32 ops
__device__ __forceinline__ float sigf(float x) {
    float e = (float)exp(-(double)x);
    return 1.0f / (1.0f + e);
}
__device__ __forceinline__ float expf_cr(float x) {
    return (float)exp((double)x);
}

struct DecParams { float aw[9]; float ah[9]; };

// ---------------- Stage A: decode boxes + exact objectness + x-threshold ----------------
// xthr correctness (r5/r6-validated):
//   Tp = 0.59999 (< 0.6f).  thr = -log(so/Tp - 1)  =>  sigmoid(thr) = Tp/so.
//   ex >= 0.6f  =>  x > thr (captured).   x <= thr  =>  ex < 0.6f (safe to miss).
//   so <= 0.59999f  =>  ex < 0.6f  =>  xthr=+INF.
__global__ __launch_bounds__(256) void decode_kernel(
        const float* __restrict__ p0, const float* __restrict__ p1,
        const float* __restrict__ p2,
        float4* __restrict__ boxes, float* __restrict__ so_arr,
        float* __restrict__ xthr_arr, DecParams dp) {
    int blk = blockIdx.x;
    int b = blk / 93;
    int rem = blk % 93;
    int a = rem / 31;
    int seg = rem % 31;
    int s, cellblk;
    if (seg < 23)      { s = 0; cellblk = seg; }
    else if (seg < 29) { s = 1; cellblk = seg - 23; }
    else               { s = 2; cellblk = seg - 29; }
    const int SS_[3]  = {76, 38, 19};
    const int HW_[3]  = {5776, 1444, 361};
    const int OFF_[3] = {0, 5776, 7220};
    const float* __restrict__ pr = (s == 0) ? p0 : (s == 1) ? p1 : p2;
    int S = SS_[s], HW = HW_[s];
    int cell = cellblk * 256 + (int)threadIdx.x;
    if (cell >= HW) return;
    const float* pb = pr + ((size_t)b * 255 + (size_t)a * 85) * (size_t)HW + cell;

    float tx  = pb[0];
    float ty  = pb[(size_t)HW];
    float tw  = pb[(size_t)2 * HW];
    float th  = pb[(size_t)3 * HW];
    float obj = pb[(size_t)4 * HW];

    float Sf = (float)S;
    float gx = (float)(cell % S);
    float gy = (float)(cell / S);
    float cx = (sigf(tx) + gx) / Sf;
    float cy = (sigf(ty) + gy) / Sf;
    float aw = dp.aw[s * 3 + a], ah = dp.ah[s * 3 + a];
    float bw = expf_cr(tw) * aw;
    float bh = expf_cr(th) * ah;
    float x1 = cx - 0.5f * bw;
    float y1 = cy - 0.5f * bh;
    int n = a * SUMHW + OFF_[s] + cell;
    boxes[(size_t)b * NN + n] = make_float4(x1, y1, x1 + bw, y1 + bh);

    float so = sigf(obj);
    size_t pidx = (size_t)b * PADNN + a * ASTRIDE + OFF_[s] + cell;
    so_arr[pidx] = so;
    float thr = __int_as_float(0x7F800000);       // +INF
    if (so > 0.59999f) {
        double arg = (double)so / 0.59999 - 1.0;
        thr = __double2float_rd(-log(arg));       // round DOWN: conservative capture
    }
    xthr_arr[pidx] = thr;
}

// ---------------- Stage B: dense stream + threshold scatter, 10-deep MLP ----------------
// grid: 16 b * 3 a * 9 cellsegs(6 s0 + 2 s1 + 1 s2) * 4 classgroups = 1728 blocks
__global__ __launch_bounds__(256) void scatter_kernel(
        const float* __restrict__ p0, const float* __restrict__ p1,
        const float* __restrict__ p2,
        const float* __restrict__ so_arr, const float* __restrict__ xthr_arr,
        unsigned int* __restrict__ klist, unsigned long long* __restrict__ vlist,
        unsigned int* __restrict__ gcnt) {
    __shared__ unsigned int       skeys[20][STAGECAP];   // 7680 B
    __shared__ unsigned long long svals[20][STAGECAP];   // 15360 B
    __shared__ unsigned int lcnt[20];
    __shared__ unsigned int lbase[20];

    int blk = blockIdx.x;
    int b = blk / 108;
    int rem = blk % 108;
    int a = rem / 36;
    int rem2 = rem % 36;
    int seg = rem2 / 4;
    int cg  = rem2 % 4;          // 20 classes per group
    int s, segi;
    if (seg < 6)      { s = 0; segi = seg; }
    else if (seg < 8) { s = 1; segi = seg - 6; }
    else              { s = 2; segi = 0; }
    const int HW_[3]  = {5776, 1444, 361};
    const int OFF_[3] = {0, 5776, 7220};
    const float* __restrict__ pr = (s == 0) ? p0 : (s == 1) ? p1 : p2;
    int HW = HW_[s], OFF = OFF_[s];
    int t = threadIdx.x;

    for (int i = t; i < 20; i += 256) lcnt[i] = 0;
    __syncthreads();

    int cell0 = segi * 1024 + t * 4;
    const float INF = __int_as_float(0x7F800000);
    float th0 = INF, th1 = INF, th2 = INF, th3 = INF;
    float so0 = 0.f, so1 = 0.f, so2 = 0.f, so3 = 0.f;
    const float* xt = xthr_arr + (size_t)b * PADNN + a * ASTRIDE + OFF;
    const float* sp = so_arr   + (size_t)b * PADNN + a * ASTRIDE + OFF;
    // for s0/s1, active threads (cell0 < HW) are always 4-aligned & full
    bool vec4 = (s != 2) && (cell0 + 3 < HW);
    if (vec4) {
        float4 tv = *(const float4*)(xt + cell0);
        float4 sv = *(const float4*)(sp + cell0);
        th0 = tv.x; th1 = tv.y; th2 = tv.z; th3 = tv.w;
        so0 = sv.x; so1 = sv.y; so2 = sv.z; so3 = sv.w;
    } else if (cell0 < HW) {
        th0 = xt[cell0];     so0 = sp[cell0];
        if (cell0 + 1 < HW) { th1 = xt[cell0 + 1]; so1 = sp[cell0 + 1]; }
        if (cell0 + 2 < HW) { th2 = xt[cell0 + 2]; so2 = sp[cell0 + 2]; }
        if (cell0 + 3 < HW) { th3 = xt[cell0 + 3]; so3 = sp[cell0 + 3]; }
    }
    int n0 = a * SUMHW + OFF + cell0;
    int cbase = cg * 20;
    int rowb = b * NCLS + cbase;
    const float* __restrict__ cp0 =
        pr + ((size_t)b * 255 + (size_t)a * 85 + 5 + (size_t)cbase) * (size_t)HW;

    auto push = [&](int g, float x, float so, int n) {
        float st = 1.0f / (1.0f + __expf(-x));   // approx sigmoid, err few ulp
        unsigned key = __float_as_uint(st * so);
        unsigned long long val =
            ((unsigned long long)__float_as_uint(x) << 32) | (unsigned)n;
        unsigned pos = atomicAdd(&lcnt[g], 1u);
        if (pos < STAGECAP) { skeys[g][pos] = key; svals[g][pos] = val; }
        else {                                   // ~never: direct global spill
            unsigned gp = atomicAdd(&gcnt[rowb + g], 1u);
            if (gp < GCAP) {
                klist[(size_t)(rowb + g) * GCAP + gp] = key;
                vlist[(size_t)(rowb + g) * GCAP + gp] = val;
            }
        }
    };

    if (vec4) {
#pragma unroll 1
        for (int hf = 0; hf < 2; ++hf) {
            // issue 10 independent global_load_dwordx4 BEFORE any consume -> deep MLP
            float4 xv[10];
            const float* cph = cp0 + (size_t)(hf * 10) * HW + cell0;
#pragma unroll
            for (int g = 0; g < 10; ++g)
                xv[g] = *(const float4*)(cph + (size_t)g * HW);
#pragma unroll
            for (int g = 0; g < 10; ++g) {
                int gg = hf * 10 + g;
                if (xv[g].x > th0) push(gg, xv[g].x, so0, n0);
                if (xv[g].y > th1) push(gg, xv[g].y, so1, n0 + 1);
                if (xv[g].z > th2) push(gg, xv[g].z, so2, n0 + 2);
                if (xv[g].w > th3) push(gg, xv[g].w, so3, n0 + 3);
            }
        }
    } else if (cell0 < HW) {                     // s2 tail (361 cells), scalar
#pragma unroll 2
        for (int g = 0; g < 20; ++g) {
            const float* __restrict__ cp = cp0 + (size_t)g * HW;
            float v0 = cp[cell0];
            float v1 = (cell0 + 1 < HW) ? cp[cell0 + 1] : 0.0f;
            float v2 = (cell0 + 2 < HW) ? cp[cell0 + 2] : 0.0f;
            float v3 = (cell0 + 3 < HW) ? cp[cell0 + 3] : 0.0f;
            if (v0 > th0) push(g, v0, so0, n0);
            if (v1 > th1) push(g, v1, so1, n0 + 1);
            if (v2 > th2) push(g, v2, so2, n0 + 2);
            if (v3 > th3) push(g, v3, so3, n0 + 3);
        }
    }
    __syncthreads();

    // flush: ONE global atomic per class, then coalesced copy
    if (t < 20) {
        unsigned m = lcnt[t]; if (m > STAGECAP) m = STAGECAP;
        lbase[t] = atomicAdd(&gcnt[rowb + t], m);
        lcnt[t] = m;
    }
    __syncthreads();
    for (int g = 0; g < 20; ++g) {
        unsigned m = lcnt[g], base = lbase[g];
        for (unsigned i = t; i < m; i += 256) {
            unsigned p = base + i;
            if (p < GCAP) {
                klist[(size_t)(rowb + g) * GCAP + p] = skeys[g][i];
                vlist[(size_t)(rowb + g) * GCAP + p] = svals[g][i];
            }
        }
    }
}

// ------- Stage C: per-(b,c) prune + exact rescore + rank-select + bitmask NMS -------
__global__ __launch_bounds__(256) void select_nms_kernel(
        const float* __restrict__ p0, const float* __restrict__ p1,
        const float* __restrict__ p2,
        const float* __restrict__ so_arr,
        const float4* __restrict__ boxes,
        const unsigned int* __restrict__ klist,
        const unsigned long long* __restrict__ vlist,
        const unsigned int* __restrict__ gcnt,
        float* __restrict__ out) {
    __shared__ unsigned long long skey[CAP];      // 8 KB (fallback needs 1024)
    __shared__ unsigned long long sorted[TOPK];   // 1 KB
    __shared__ unsigned long long msk[TOPK][2];   // 2 KB
    __shared__ unsigned long long aliveLDS[2];
    __shared__ unsigned int hist[512];
    __shared__ unsigned int sums[256];
    __shared__ float4 bxs4[TOPK];                 // 2 KB
    __shared__ float pvs[TOPK];
    __shared__ unsigned int sh_bin, sh_above, gcount;

    int t = threadIdx.x;
    int bid = blockIdx.x;          // b*80 + c
    int b = bid / NCLS;
    int c = bid % NCLS;
    const float4* brow = boxes + (size_t)b * NN;

    // all-pairs rank selection: keys unique (low bits carry ~n) => rank is a permutation
    auto rankSelect = [&](unsigned Gc) {
        if (t < TOPK) sorted[t] = 0ULL;
        __syncthreads();
        unsigned i0 = t, i1 = t + 256, i2 = t + 512, i3 = t + 768;
        bool v0 = i0 < Gc, v1 = i1 < Gc, v2 = i2 < Gc, v3 = i3 < Gc;
        unsigned long long o0 = v0 ? skey[i0] : 0ULL;
        unsigned long long o1 = v1 ? skey[i1] : 0ULL;
        unsigned long long o2 = v2 ? skey[i2] : 0ULL;
        unsigned long long o3 = v3 ? skey[i3] : 0ULL;
        unsigned r0 = 0, r1 = 0, r2 = 0, r3 = 0;
        for (unsigned j = 0; j < Gc; ++j) {
            unsigned long long kj = skey[j];      // wave-uniform addr -> LDS broadcast
            r0 += (kj > o0); r1 += (kj > o1); r2 += (kj > o2); r3 += (kj > o3);
        }
        if (v0 && r0 < TOPK) sorted[r0] = o0;
        if (v1 && r1 < TOPK) sorted[r1] = o1;
        if (v2 && r2 < TOPK) sorted[r2] = o2;
        if (v3 && r3 < TOPK) sorted[r3] = o3;
        __syncthreads();
    };

    unsigned G = gcnt[bid];
    // G < TOPK => true top-128 needs sub-0.6 elements the scatter never captured
    bool fb = (G > GCAP) || (G < TOPK);
    if (!fb) {
        const unsigned int* kl = klist + (size_t)bid * GCAP;
        for (int i = t; i < 512; i += 256) hist[i] = 0;
        if (t == 0) gcount = 0;
        __syncthreads();
        // --- pass 1: 512-bin histogram of stored approx keys (16384-ulp bins) ---
        for (unsigned i = t; i < G; i += 256) {
            unsigned bin = (kl[i] - KB2) >> 14;
            if (bin > 511u) bin = 511u;
            atomicAdd(&hist[bin], 1u);
        }
        __syncthreads();
        unsigned m0 = hist[2 * t], m1 = hist[2 * t + 1];
        sums[t] = m0 + m1;
        __syncthreads();
        for (int d = 1; d < 256; d <<= 1) {
            unsigned v = sums[t];
            if (t + d < 256) v += sums[t + d];
            __syncthreads();
            sums[t] = v;
            __syncthreads();
        }
        unsigned si = sums[t], se = si - (m0 + m1);
        if (se < TOPK && TOPK <= si) {              // unique crossing thread
            if (TOPK <= se + m1) { sh_bin = 2 * t + 1; sh_above = se; }
            else                 { sh_bin = 2 * t;     sh_above = se + m1; }
        }
        __syncthreads();
        unsigned B1 = sh_bin, above1 = sh_above;
        unsigned cntB = hist[B1];
        unsigned binlo = KB2 + (B1 << 14);
        if (above1 + cntB > PRUNECAP - 64) {
            fb = true;                               // fat bin (~never): full re-scan
        } else {
            // --- pass 2: gather keys >= binlo - 256ulp (validated margin),
            //             exact-rescore survivors only ---
            unsigned gth = binlo - 256;
            for (unsigned i = t; i < G; i += 256) {
                if (kl[i] >= gth) {
                    unsigned pos = atomicAdd(&gcount, 1u);
                    if (pos < PRUNECAP) {
                        unsigned long long v = vlist[(size_t)bid * GCAP + i];
                        unsigned xb = (unsigned)(v >> 32);
                        unsigned n  = (unsigned)(v & 0xFFFFFFFFu);
                        unsigned a  = n / SUMHW;
                        unsigned r  = n - a * SUMHW;
                        float so = so_arr[(size_t)b * PADNN + a * ASTRIDE + r];
                        float ex = so * sigf(__uint_as_float(xb));   // ref-identical chain
                        skey[pos] = (ex > 0.3f)
                            ? (((unsigned long long)__float_as_uint(ex) << 32) |
                               (unsigned)(~n))
                            : (unsigned long long)(unsigned)(~n);    // unique dead key
                    }
                }
            }
            __syncthreads();
            if (gcount > PRUNECAP) fb = true;        // overflow (~never): full re-scan
            if (!fb) {
                unsigned Gc = gcount;
                rankSelect(Gc);
                // success <=> kept 128th has ex >= 0.6f (every scatter-missed elem < 0.6f)
                bool ok = (Gc >= TOPK) && ((unsigned)(sorted[TOPK - 1] >> 32) >= SBITS);
                if (!ok) fb = true;
            }
        }
    }

    if (fb) {
        // ---- full re-scan fallback (rounds 3/4 validated); never taken on bench data ----
        auto scanScalar = [&](auto&& body) {
#pragma unroll
            for (int s = 0; s < 3; ++s) {
                const float* __restrict__ pr = (s == 0) ? p0 : (s == 1) ? p1 : p2;
                const int HW  = (s == 0) ? 5776 : (s == 1) ? 1444 : 361;
                const int OFF = (s == 0) ? 0 : (s == 1) ? 5776 : 7220;
#pragma unroll
                for (int a = 0; a < 3; ++a) {
                    const float* __restrict__ cp =
                        pr + ((size_t)b * 255 + (size_t)a * 85 + 5 + (size_t)c) * (size_t)HW;
                    const float* __restrict__ sop =
                        so_arr + (size_t)b * PADNN + a * ASTRIDE + OFF;
                    int n0 = a * SUMHW + OFF;
                    for (int i = t; i < HW; i += 256) {
                        float so = sop[i];
                        if (so <= 0.2999f) continue;
                        float x = cp[i];
                        float st = 1.0f / (1.0f + __expf(-x));
                        float sca = st * so;
                        if (sca > 0.2999f) body(sca, x, so, n0 + i);
                    }
                }
            }
        };
        __syncthreads();
        for (int i = t; i < 512; i += 256) hist[i] = 0;
        if (t == 0) gcount = 0;
        __syncthreads();
        scanScalar([&](float sca, float, float, int) {
            unsigned bin = (__float_as_uint(sca) - KEYBASE) >> 15;
            if (bin > 511u) bin = 511u;
            atomicAdd(&hist[bin], 1u);
        });
        __syncthreads();
        unsigned m0 = hist[2 * t], m1 = hist[2 * t + 1];
        sums[t] = m0 + m1;
        __syncthreads();
        for (int d = 1; d < 256; d <<= 1) {
            unsigned v = sums[t];
            if (t + d < 256) v += sums[t + d];
            __syncthreads();
            sums[t] = v;
            __syncthreads();
        }
        unsigned total = sums[0];
        bool gatherAll = (total < TOPK);
        unsigned gth = 0;
        if (!gatherAll) {
            unsigned si = sums[t], se = si - (m0 + m1);
            if (se < TOPK && TOPK <= si) {
                if (TOPK <= se + m1) { sh_bin = 2 * t + 1; sh_above = se; }
                else                 { sh_bin = 2 * t;     sh_above = se + m1; }
            }
            __syncthreads();
            unsigned B1 = sh_bin, above1 = sh_above;
            unsigned cntB = hist[B1];
            unsigned binlo = KEYBASE + (B1 << 15);
            __syncthreads();
            if (above1 + cntB <= 768) {
                gth = binlo - 256;              // 256-ulp margin >> approx err (r3-validated)
            } else {
                if (t < 256) hist[t] = 0;
                __syncthreads();
                scanScalar([&](float sca, float, float, int) {
                    unsigned key = __float_as_uint(sca);
                    if (((key - KEYBASE) >> 15) == B1) {
                        unsigned sub = (key - binlo) >> 7;
                        if (sub > 255u) sub = 255u;
                        atomicAdd(&hist[sub], 1u);
                    }
                });
                __syncthreads();
                unsigned R2 = TOPK - above1;
                unsigned sl = hist[t];
                sums[t] = sl;
                __syncthreads();
                for (int d = 1; d < 256; d <<= 1) {
                    unsigned v = sums[t];
                    if (t + d < 256) v += sums[t + d];
                    __syncthreads();
                    sums[t] = v;
                    __syncthreads();
                }
                unsigned si2 = sums[t], se2 = si2 - sl;
                if (se2 < R2 && R2 <= si2) sh_bin = (unsigned)t;
                __syncthreads();
                gth = binlo + (sh_bin << 7) - 256;
            }
        }
        __syncthreads();
        scanScalar([&](float sca, float x, float so, int n) {
            unsigned key = __float_as_uint(sca);
            if (gatherAll || key >= gth) {
                unsigned pos = atomicAdd(&gcount, 1u);
                if (pos < CAP) {
                    float ex = so * sigf(x);
                    skey[pos] = (ex > 0.3f)
                        ? (((unsigned long long)__float_as_uint(ex) << 32) |
                           (unsigned)(~(unsigned)n))
                        : (unsigned long long)(unsigned)(~(unsigned)n);
                }
            }
        });
        __syncthreads();
        unsigned Gc = gcount < CAP ? gcount : CAP;
        rankSelect(Gc);
    }

    // --- extract top-128 (sorted[rank]) ---
    if (t < TOPK) {
        unsigned long long e = sorted[t];
        bool vld = (e != 0ULL);
        float sc = __uint_as_float((unsigned)(e >> 32));
        unsigned n = ~(unsigned)(e & 0xFFFFFFFFu);
        float4 bb = make_float4(0.f, 0.f, 0.f, 0.f);
        if (vld) bb = brow[n];
        bxs4[t] = bb;
        pvs[t] = vld ? sc : -1.0f;    // dead-unique key -> sc = 0.0 (never kept/suppresses)
    }
    __syncthreads();

    // --- bitmask NMS: parallel IoU mask build, then wave-0 bitmask greedy ---
    {
        int i = t >> 1, h = t & 1;
        float4 bi = bxs4[i];
        float ai = (bi.z - bi.x) * (bi.w - bi.y);
        unsigned long long m = 0;
        int jb = h << 6;
        for (int k = 0; k < 64; ++k) {
            int j = jb + k;
            float4 bj = bxs4[j];
            float aj = (bj.z - bj.x) * (bj.w - bj.y);
            float xx1 = fmaxf(bi.x, bj.x), yy1 = fmaxf(bi.y, bj.y);
            float xx2 = fminf(bi.z, bj.z), yy2 = fminf(bi.w, bj.w);
            float ww = fmaxf(xx2 - xx1, 0.0f), hh = fmaxf(yy2 - yy1, 0.0f);
            float inter = ww * hh;
            float iou = inter / (ai + aj - inter);
            if (j > i && iou > 0.45f) m |= (1ull << k);
        }
        msk[i][h] = m;
    }
    __syncthreads();
    if (t < 64) {
        unsigned long long A0 = __ballot(pvs[t] > 0.0f);
        unsigned long long A1 = __ballot(pvs[t + 64] > 0.0f);
        for (int i = 0; i < 64; ++i) {
            if ((A0 >> i) & 1) { A0 &= ~msk[i][0]; A1 &= ~msk[i][1]; }
        }
        for (int i = 0; i < 64; ++i) {
            if ((A1 >> i) & 1) { A1 &= ~msk[64 + i][1]; }   // msk[i>=64][0] is all-zero (j>i)
        }
        if (t == 0) { aliveLDS[0] = A0; aliveLDS[1] = A1; }
    }
    __syncthreads();

    // --- write [K,6] = x1,y1,x2,y2,score,class ---
    unsigned long long A0 = aliveLDS[0], A1 = aliveLDS[1];
    float* o = out + (size_t)bid * TOPK * 6;
    for (int i = t; i < TOPK; i += 256) {
        bool alive = (i < 64) ? ((A0 >> i) & 1) : ((A1 >> (i - 64)) & 1);
        float p = pvs[i];
        bool kept = alive && (p > 0.0f);
        float4 bb = bxs4[i];
        o[i * 6 + 0] = kept ? bb.x : 0.0f;
        o[i * 6 + 1] = kept ? bb.y : 0.0f;
        o[i * 6 + 2] = kept ? bb.z : 0.0f;
        o[i * 6 + 3] = kept ? bb.w : 0.0f;
        o[i * 6 + 4] = kept ? p : 0.0f;
        o[i * 6 + 5] = (float)c;
    }
}

extern "C" void kernel_launch(void* const* d_in, const int* in_sizes, int n_in,
                              void* d_out, int out_size, void* d_ws, size_t ws_size,
                              hipStream_t stream) {
    const float* p0 = (const float*)d_in[0];
    const float* p1 = (const float*)d_in[1];
    const float* p2 = (const float*)d_in[2];
    float* out = (float*)d_out;

    char* ws = (char*)d_ws;
    unsigned int* gcnt = (unsigned int*)ws;                        // 5120 B (pad 8192)
    float4* boxes = (float4*)(ws + 8192);                          // 5,822,208 B
    float*  so_arr  = (float*)(ws + 5830400ull);                   // 1,456,128 B
    float*  xthr    = (float*)(ws + 7286528ull);                   // 1,456,128 B
    unsigned int* klist = (unsigned int*)(ws + 8742656ull);        // 10,485,760 B
    unsigned long long* vlist = (unsigned long long*)(ws + 19228416ull); // 20,971,520 B

    static const float ANC[3][3][2] = {
        {{12, 16}, {19, 36}, {40, 28}},
        {{36, 75}, {76, 55}, {72, 146}},
        {{142, 110}, {192, 243}, {459, 401}},
    };
    static const int RED[3] = {8, 16, 32};
    static const int SS[3]  = {76, 38, 19};

    DecParams dp;
    for (int s = 0; s < 3; ++s)
        for (int a = 0; a < 3; ++a) {
            float Sf = (float)SS[s];
            dp.aw[s * 3 + a] = (ANC[s][a][0] / (float)RED[s]) / Sf;  // same f32 chain as ref
            dp.ah[s * 3 + a] = (ANC[s][a][1] / (float)RED[s]) / Sf;
        }

    hipMemsetAsync(gcnt, 0, BATCH * NCLS * sizeof(unsigned int), stream);
    decode_kernel<<<BATCH * 93, 256, 0, stream>>>(p0, p1, p2, boxes, so_arr, xthr, dp);
    scatter_kernel<<<1728, 256, 0, stream>>>(p0, p1, p2, so_arr, xthr, klist, vlist, gcnt);
    select_nms_kernel<<<BATCH * NCLS, 256, 0, stream>>>(p0, p1, p2, so_arr, boxes,
                                                        klist, vlist, gcnt, out);
}